// Round 4
// baseline (4670.343 us; speedup 1.0000x reference)
//
#include <hip/hip_runtime.h>
#include <cmath>

// ---------------------------------------------------------------------------
// RPN head on MI355X. fp32 throughout; conv FMA chain order (ic,ky,kx asc,
// fmaf(w,x,acc)) and the head's 16x16 two-level reduction are bit-exact vs
// the np reference (R1-R3 measured absmax 0.0) — preserve both exactly.
//
// R4 (theory: R3 was latency-serialized per (ic,ky) — the uniform row-bounds
// branch blocked cross-iteration pipelining of the scalar X loads; only 96
// FMA cycles per ~1.3k-cycle iteration -> 37% issue duty):
//   - 2 output rows x 16 px per block (acc[2][16]): 4 shared input rows and
//     9 shared weight dwords per ic feed 288 wave-FMAs (576 issue cyc)
//   - branch-free X loads: clamped row pointer + uniform bitmask AND gives
//     exact +0.0 for halo rows/cols (fmaf(w,0,acc)=acc, bit-exact)
//   - epilogue unchanged but run twice (once per output row) over a 16KB
//     LDS t-tile; LDS ~17.3KB, __launch_bounds__(256,6)
// ---------------------------------------------------------------------------

#define NTOT_PER_IMG 261888   // sum of H*W*3 over levels
#define ATOT_PER_IMG 4768     // 4*1000 + 768

__constant__ int c_NLVL[5] = {196608, 49152, 12288, 3072, 768};
__constant__ int c_KLVL[5] = {1000, 1000, 1000, 1000, 768};
__constant__ int c_LOFF[5] = {0, 196608, 245760, 258048, 261120};
__constant__ int c_AOFF[5] = {0, 1000, 2000, 3000, 4000};

struct Anch { float cx1[3]; float cy1[3]; };
struct ConvCfg { Anch an[5]; };

// ------------------------------ weight transpose ---------------------------
__global__ __launch_bounds__(256) void wtrans(const float* __restrict__ Wsrc,
                                              float* __restrict__ Wt) {
  __shared__ float T[16][17];
  int k0 = blockIdx.x * 16;   // 2304/16 = 144
  int o0 = blockIdx.y * 16;   // 256/16  = 16
  int i = threadIdx.x >> 4, j = threadIdx.x & 15;
  T[i][j] = Wsrc[(size_t)(o0 + i) * 2304 + (k0 + j)];
  __syncthreads();
  Wt[(size_t)(k0 + i) * 256 + (o0 + j)] = T[j][i];
}

// ------------------------------ fused conv ---------------------------------
// One block = 2 consecutive output rows x 16 px x all 256 oc.
__global__ __launch_bounds__(256, 6) void conv_all(
    const float* __restrict__ f0, const float* __restrict__ f1,
    const float* __restrict__ f2, const float* __restrict__ f3,
    const float* __restrict__ f4, const float* __restrict__ Wt,
    const float* __restrict__ convb, const float* __restrict__ clsw,
    const float* __restrict__ clsb, const float* __restrict__ bboxw,
    const float* __restrict__ bboxb, float* __restrict__ scoresOut,
    float4* __restrict__ boxesOut, ConvCfg cfg) {
  __shared__ __align__(16) float sm[4096 + 272];  // t[16][256] + Red2[16][17]
  float* tl = sm;
  float* Red2 = sm + 4096;

  // ---- decode level / image / tile from blockIdx (row-pair tiles) ----
  int b = blockIdx.x;
  const float* feat;
  int lvl, img, gy2, bx, H, stride, lvlOff;
  if (b < 4096) {
    lvl = 0; feat = f0; H = 256; stride = 4; lvlOff = 0;
    img = b >> 11; int r = b & 2047; gy2 = r >> 4; bx = r & 15;
  } else if (b < 5120) {
    lvl = 1; feat = f1; H = 128; stride = 8; lvlOff = 196608;
    int rb = b - 4096; img = rb >> 9; int r = rb & 511; gy2 = r >> 3; bx = r & 7;
  } else if (b < 5376) {
    lvl = 2; feat = f2; H = 64; stride = 16; lvlOff = 245760;
    int rb = b - 5120; img = rb >> 7; int r = rb & 127; gy2 = r >> 2; bx = r & 3;
  } else if (b < 5440) {
    lvl = 3; feat = f3; H = 32; stride = 32; lvlOff = 258048;
    int rb = b - 5376; img = rb >> 5; int r = rb & 31; gy2 = r >> 1; bx = r & 1;
  } else {
    lvl = 4; feat = f4; H = 16; stride = 64; lvlOff = 261120;
    int rb = b - 5440; img = rb >> 3; gy2 = rb & 7; bx = 0;
  }
  const int W = H;
  const int HW = H * W;
  const int x0 = bx * 16;
  const int gy0 = gy2 * 2;
  const Anch an = cfg.an[lvl];

  const int tid = threadIdx.x;
  const int lane = tid & 63;
  const int wav = __builtin_amdgcn_readfirstlane(tid >> 6);
  const int oc = wav * 64 + lane;

  const float* f = feat + (size_t)img * 256 * HW;

  float acc0[16], acc1[16];
#pragma unroll
  for (int p = 0; p < 16; p++) { acc0[p] = 0.f; acc1[p] = 0.f; }

  const bool leftEdge = (x0 == 0);
  const bool rightEdge = (x0 + 16 >= W);
  const unsigned mskL = leftEdge ? 0u : 0xFFFFFFFFu;
  const unsigned mskR = rightEdge ? 0u : 0xFFFFFFFFu;
  const int offL = leftEdge ? 0 : -1;
  const int offR = rightEdge ? 15 : 16;

  // branch-free uniform row load: clamped pointer + bitmask AND (exact +0.0)
#define LOADROW(arr, rowi)                                                   \
  {                                                                          \
    int row_ = (rowi);                                                       \
    unsigned msk_ = (row_ >= 0 && row_ < H) ? 0xFFFFFFFFu : 0u;              \
    int rc_ = row_ < 0 ? 0 : (row_ >= H ? H - 1 : row_);                     \
    const float* rp_ = pl + (size_t)rc_ * W + x0;                            \
    arr[0] = __uint_as_float(__float_as_uint(rp_[offL]) & msk_ & mskL);      \
    _Pragma("unroll")                                                        \
    for (int j_ = 0; j_ < 16; j_++)                                          \
      arr[j_ + 1] = __uint_as_float(__float_as_uint(rp_[j_]) & msk_);        \
    arr[17] = __uint_as_float(__float_as_uint(rp_[offR]) & msk_ & mskR);     \
  }

  // 3 kx taps into one acc row from one input row (kx ascending, bit-exact)
#define FMA3(accA, arr, w0_, w1_, w2_)                                       \
  {                                                                          \
    _Pragma("unroll")                                                        \
    for (int p_ = 0; p_ < 16; p_++)                                          \
      accA[p_] = __builtin_fmaf(w0_, arr[p_], accA[p_]);                     \
    _Pragma("unroll")                                                        \
    for (int p_ = 0; p_ < 16; p_++)                                          \
      accA[p_] = __builtin_fmaf(w1_, arr[p_ + 1], accA[p_]);                 \
    _Pragma("unroll")                                                        \
    for (int p_ = 0; p_ < 16; p_++)                                          \
      accA[p_] = __builtin_fmaf(w2_, arr[p_ + 2], accA[p_]);                 \
  }

#pragma unroll 1
  for (int ic = 0; ic < 256; ic++) {
    const float* pl = f + (size_t)ic * HW;
    const float* wrow = Wt + (size_t)ic * 9 * 256 + oc;
    // 9 weight dwords (coalesced per wave, L2-hot)
    float w00 = wrow[0 * 256], w01 = wrow[1 * 256], w02 = wrow[2 * 256];
    float w10 = wrow[3 * 256], w11 = wrow[4 * 256], w12 = wrow[5 * 256];
    float w20 = wrow[6 * 256], w21 = wrow[7 * 256], w22 = wrow[8 * 256];
    // 4 input rows (uniform -> scalar loads), straight-line
    float R0[18], R1[18], R2[18], R3[18];
    LOADROW(R0, gy0 - 1)
    LOADROW(R1, gy0)
    LOADROW(R2, gy0 + 1)
    LOADROW(R3, gy0 + 2)
    // ky=0
    FMA3(acc0, R0, w00, w01, w02)
    FMA3(acc1, R1, w00, w01, w02)
    // ky=1
    FMA3(acc0, R1, w10, w11, w12)
    FMA3(acc1, R2, w10, w11, w12)
    // ky=2
    FMA3(acc0, R2, w20, w21, w22)
    FMA3(acc1, R3, w20, w21, w22)
  }
#undef LOADROW
#undef FMA3

  // ---- epilogue: two passes (one per output row) ----
  const float cb = convb[oc];
  const float BCLIP = (float)4.135166556742356;  // log(1000/16)
  const size_t base = (size_t)img * NTOT_PER_IMG + lvlOff;

#pragma unroll
  for (int rr = 0; rr < 2; rr++) {
    const int gy = gy0 + rr;
#pragma unroll
    for (int p = 0; p < 16; p++)
      tl[p * 256 + oc] = fmaxf((rr ? acc1[p] : acc0[p]) + cb, 0.f);
    __syncthreads();

    // heads: per (px, c) dot over 256 oc in 16x16 two-level order
    if (tid < 240) {
      int px = tid / 15, c = tid - px * 15;
      const float* wr0 = (c < 3) ? (clsw + c * 256) : (bboxw + (c - 3) * 256);
      float bb = (c < 3) ? clsb[c] : bboxb[c - 3];
      const float* trow = &tl[px * 256];
      float tot = 0.f;
#pragma unroll
      for (int g = 0; g < 16; g++) {
        const float* wr = wr0 + g * 16;
        const float* tr = trow + g * 16;
        float s = 0.f;
#pragma unroll
        for (int i = 0; i < 16; i++) s += wr[i] * tr[i];
        tot += s;
      }
      Red2[px * 17 + c] = tot + bb;
    }
    __syncthreads();

    // decode: one (pixel, anchor) per thread
    if (tid < 48) {
      int px = tid / 3, a = tid - px * 3;
      int gx = x0 + px;
      float sc = Red2[px * 17 + a];
      float dxv = Red2[px * 17 + 3 + a * 4 + 0];
      float dyv = Red2[px * 17 + 3 + a * 4 + 1];
      float dwv = Red2[px * 17 + 3 + a * 4 + 2];
      float dhv = Red2[px * 17 + 3 + a * 4 + 3];
      float sx = (float)(gx * stride), sy = (float)(gy * stride);
      float x1 = __fadd_rn(sx, an.cx1[a]);
      float x2 = __fsub_rn(sx, an.cx1[a]);
      float y1 = __fadd_rn(sy, an.cy1[a]);
      float y2 = __fsub_rn(sy, an.cy1[a]);
      float wdt = __fadd_rn(__fsub_rn(x2, x1), 1.0f);
      float hgt = __fadd_rn(__fsub_rn(y2, y1), 1.0f);
      float ctx = __fadd_rn(x1, __fmul_rn(0.5f, wdt));
      float cty = __fadd_rn(y1, __fmul_rn(0.5f, hgt));
      float dw = fminf(dwv, BCLIP), dh = fminf(dhv, BCLIP);
      float pcx = __fadd_rn(__fmul_rn(dxv, wdt), ctx);
      float pcy = __fadd_rn(__fmul_rn(dyv, hgt), cty);
      float pw = __fmul_rn(expf(dw), wdt);
      float ph = __fmul_rn(expf(dh), hgt);
      float hw = __fmul_rn(0.5f, pw), hh = __fmul_rn(0.5f, ph);
      float bx1 = __fsub_rn(pcx, hw);
      float by1 = __fsub_rn(pcy, hh);
      float bx2 = __fsub_rn(__fadd_rn(pcx, hw), 1.0f);
      float by2 = __fsub_rn(__fadd_rn(pcy, hh), 1.0f);
      bx1 = fminf(fmaxf(bx1, 0.f), 1023.f);
      by1 = fminf(fmaxf(by1, 0.f), 1023.f);
      bx2 = fminf(fmaxf(bx2, 0.f), 1023.f);
      by2 = fminf(fmaxf(by2, 0.f), 1023.f);
      int g = gy * W + gx;
      size_t o = base + (size_t)g * 3 + a;
      scoresOut[o] = sc;
      boxesOut[o] = make_float4(bx1, by1, bx2, by2);
    }
    __syncthreads();
  }
}

// ------------------------------ top-k --------------------------------------
__device__ __forceinline__ unsigned fkey(float f) {
  unsigned b = __float_as_uint(f);
  return (b & 0x80000000u) ? ~b : (b | 0x80000000u);
}
__device__ __forceinline__ float funkey(unsigned u) {
  unsigned b = (u & 0x80000000u) ? (u & 0x7fffffffu) : ~u;
  return __uint_as_float(b);
}

// Exact lax.top_k: value desc, index asc on ties. Radix-select the threshold,
// bisect an index cut for boundary ties, bitonic-sort packed (key, ~idx).
template <bool FINAL>
__global__ __launch_bounds__(1024) void topk_kernel(
    const float* __restrict__ scoresIn, const float4* __restrict__ boxesIn,
    float* __restrict__ scoresOut, float4* __restrict__ boxesOut,
    float* __restrict__ finalOut) {
  __shared__ unsigned long long keys[1024];
  __shared__ unsigned hist[256];
  __shared__ unsigned s_comm[4];
  int lvl = 0, img, N, k;
  const float* src;
  const float4* bsrc;
  if (FINAL) {
    img = blockIdx.x; N = ATOT_PER_IMG; k = 1000;
    src = scoresIn + (size_t)img * ATOT_PER_IMG;
    bsrc = boxesIn + (size_t)img * ATOT_PER_IMG;
  } else {
    lvl = blockIdx.x; img = blockIdx.y;
    N = c_NLVL[lvl]; k = c_KLVL[lvl];
    src = scoresIn + (size_t)img * NTOT_PER_IMG + c_LOFF[lvl];
    bsrc = boxesIn + (size_t)img * NTOT_PER_IMG + c_LOFF[lvl];
  }
  const int tid = threadIdx.x;

  unsigned pref = 0, pmask = 0, krem = (unsigned)k, cntT = 0;
  for (int pass = 3; pass >= 0; pass--) {
    int shift = pass * 8;
    if (tid < 256) hist[tid] = 0;
    __syncthreads();
    for (int i = tid; i < N; i += 1024) {
      unsigned u = fkey(src[i]);
      if ((u & pmask) == pref) atomicAdd(&hist[(u >> shift) & 255], 1u);
    }
    __syncthreads();
    if (tid == 0) {
      unsigned cum = 0;
      for (int d = 255; d >= 0; d--) {
        unsigned c = hist[d];
        if (cum + c >= krem) {
          s_comm[0] = krem - cum; s_comm[1] = c; s_comm[2] = (unsigned)d;
          break;
        }
        cum += c;
      }
    }
    __syncthreads();
    krem = s_comm[0]; cntT = s_comm[1];
    pref |= s_comm[2] << shift;
    pmask |= 0xFFu << shift;
    __syncthreads();
  }
  const unsigned T = pref, r = krem;
  unsigned m = (unsigned)N;
  if (r < cntT) {  // boundary ties: smallest r indices among {u == T}
    unsigned lo = 0, hi = (unsigned)N;
    while (lo < hi) {
      unsigned mid = (lo + hi) >> 1;
      if (tid == 0) s_comm[3] = 0;
      __syncthreads();
      for (unsigned i = tid; i < mid; i += 1024)
        if (fkey(src[i]) == T) atomicAdd(&s_comm[3], 1u);
      __syncthreads();
      unsigned c = s_comm[3];
      __syncthreads();
      if (c >= r) hi = mid; else lo = mid + 1;
    }
    m = lo;
  }
  if (tid == 0) s_comm[3] = 0;
  __syncthreads();
  for (int i = tid; i < N; i += 1024) {
    unsigned u = fkey(src[i]);
    if (u > T || (u == T && (unsigned)i < m)) {
      unsigned p = atomicAdd(&s_comm[3], 1u);
      if (p < 1024)
        keys[p] = ((unsigned long long)u << 32) | (unsigned)(~(unsigned)i);
    }
  }
  __syncthreads();
  if (tid >= k) keys[tid] = 0ull;  // pad; sorts to the end
  __syncthreads();
  // bitonic sort, descending
  for (unsigned k2 = 2; k2 <= 1024; k2 <<= 1) {
    for (unsigned j = k2 >> 1; j > 0; j >>= 1) {
      unsigned i = tid, ixj = i ^ j;
      if (ixj > i) {
        unsigned long long a = keys[i], b = keys[ixj];
        bool sw = ((i & k2) == 0) ? (a < b) : (a > b);
        if (sw) { keys[i] = b; keys[ixj] = a; }
      }
      __syncthreads();
    }
  }
  if (tid < k) {
    unsigned long long key = keys[tid];
    unsigned u = (unsigned)(key >> 32);
    unsigned idx = ~((unsigned)key);
    float sc = funkey(u);
    float4 b = bsrc[idx];
    if (FINAL) {
      float* o = finalOut + ((size_t)img * 1000 + tid) * 5;
      o[0] = b.x; o[1] = b.y; o[2] = b.z; o[3] = b.w; o[4] = sc;
    } else {
      scoresOut[(size_t)img * ATOT_PER_IMG + c_AOFF[lvl] + tid] = sc;
      boxesOut[(size_t)img * ATOT_PER_IMG + c_AOFF[lvl] + tid] = b;
    }
  }
}

// ------------------------------ NMS ----------------------------------------
__global__ __launch_bounds__(256) void nms_matrix(
    const float4* __restrict__ allb, unsigned long long* __restrict__ supp) {
  int lvl = blockIdx.x, img = blockIdx.y, rb = blockIdx.z;
  int k = c_KLVL[lvl];
  int task = img * 5 + lvl;
  const float4* src = allb + (size_t)img * ATOT_PER_IMG + c_AOFF[lvl];
  __shared__ float4 bb[1000];
  __shared__ float ar[1000];
  for (int j = threadIdx.x; j < k; j += 256) {
    float4 b = src[j];
    bb[j] = b;
    ar[j] = __fmul_rn(__fsub_rn(b.z, b.x), __fsub_rn(b.w, b.y));
  }
  __syncthreads();
  int i = rb * 256 + threadIdx.x;
  if (i < k) {
    float4 bi = bb[i];
    float ai = ar[i];
    unsigned long long* row = supp + ((size_t)task * 1024 + i) * 16;
    int jw0 = i >> 6;
    for (int jw = 0; jw < jw0; jw++) row[jw] = 0ull;
    for (int jw = jw0; jw < 16; jw++) {
      unsigned long long bits = 0;
      int jbase = jw * 64;
      for (int jj = 0; jj < 64; jj++) {
        int j = jbase + jj;
        if (j > i && j < k) {
          float4 bj = bb[j];
          float ltx = fmaxf(bi.x, bj.x), lty = fmaxf(bi.y, bj.y);
          float rbx = fminf(bi.z, bj.z), rby = fminf(bi.w, bj.w);
          float wx = fmaxf(__fsub_rn(rbx, ltx), 0.f);
          float wy = fmaxf(__fsub_rn(rby, lty), 0.f);
          float inter = __fmul_rn(wx, wy);
          float den = __fadd_rn(__fsub_rn(__fadd_rn(ai, ar[j]), inter), 1e-9f);
          if (__fdiv_rn(inter, den) > 0.7f) bits |= 1ull << jj;
        }
      }
      row[jw] = bits;
    }
  }
}

__global__ __launch_bounds__(64) void nms_scan(
    const float* __restrict__ topS, const unsigned long long* __restrict__ supp,
    float* __restrict__ fscore) {
  int lvl = blockIdx.x, img = blockIdx.y;
  int k = c_KLVL[lvl];
  int task = img * 5 + lvl;
  int lane = threadIdx.x;
  const unsigned long long* base = supp + (size_t)task * 1024 * 16;
  unsigned long long rem = 0, keep = 0;  // lane l<16 holds 64-bit word l
  for (int b0 = 0; b0 < k; b0 += 16) {
    unsigned long long buf[16];
#pragma unroll
    for (int t = 0; t < 16; t++) {
      int i = b0 + t;
      buf[t] = (lane < 16 && i < k) ? base[(size_t)i * 16 + lane] : 0ull;
    }
#pragma unroll
    for (int t = 0; t < 16; t++) {
      int i = b0 + t;
      if (i >= k) break;
      int wi = i >> 6, bi = i & 63;
      unsigned long long rw = __shfl(rem, wi);
      if (!((rw >> bi) & 1ull)) {  // i survives: suppress its row
        rem |= buf[t];
        if (lane == wi) keep |= (1ull << bi);
      }
    }
  }
  const float* ts = topS + (size_t)img * ATOT_PER_IMG + c_AOFF[lvl];
  float* fs = fscore + (size_t)img * ATOT_PER_IMG + c_AOFF[lvl];
  for (int i = lane; i < k; i += 64) {
    int wi = i >> 6;
    unsigned long long kw = __shfl(keep, wi);
    fs[i] = ((kw >> (i & 63)) & 1ull) ? ts[i] : -1e9f;
  }
}

// ------------------------------ host ---------------------------------------
static Anch mkAnch(double size) {
  Anch a;
  const double R[3] = {0.5, 1.0, 2.0};
  for (int i = 0; i < 3; i++) {
    double w = size * sqrt(1.0 / R[i]);
    double h = size * sqrt(R[i]);
    a.cx1[i] = (float)(-w / 2.0);
    a.cy1[i] = (float)(-h / 2.0);
  }
  return a;
}

extern "C" void kernel_launch(void* const* d_in, const int* in_sizes, int n_in,
                              void* d_out, int out_size, void* d_ws,
                              size_t ws_size, hipStream_t stream) {
  (void)in_sizes; (void)n_in; (void)out_size; (void)ws_size;
  const float* f0 = (const float*)d_in[0];
  const float* f1 = (const float*)d_in[1];
  const float* f2 = (const float*)d_in[2];
  const float* f3 = (const float*)d_in[3];
  const float* f4 = (const float*)d_in[4];
  const float* conv_w = (const float*)d_in[5];
  const float* conv_b = (const float*)d_in[6];
  const float* cls_w  = (const float*)d_in[7];
  const float* cls_b  = (const float*)d_in[8];
  const float* bbox_w = (const float*)d_in[9];
  const float* bbox_b = (const float*)d_in[10];
  float* out = (float*)d_out;

  // workspace layout (floats), all 16B-aligned; total ~14.4 MB
  float* wsf = (float*)d_ws;
  float* Wt     = wsf;                      // 589824
  float* scores = Wt + 589824;              // 2*261888
  float* boxes  = scores + 2 * NTOT_PER_IMG;       // 2*261888*4
  float* topS   = boxes + (size_t)2 * NTOT_PER_IMG * 4;  // 2*4768
  float* allb   = topS + 2 * ATOT_PER_IMG;         // 2*4768*4
  float* fscore = allb + (size_t)2 * ATOT_PER_IMG * 4;   // 2*4768
  unsigned long long* supp =
      (unsigned long long*)(fscore + 2 * ATOT_PER_IMG);  // 10*1024*16 u64

  wtrans<<<dim3(144, 16), 256, 0, stream>>>(conv_w, Wt);

  ConvCfg cfg;
  const double SZ[5] = {32, 64, 128, 256, 512};
  for (int l = 0; l < 5; l++) cfg.an[l] = mkAnch(SZ[l]);

  conv_all<<<5456, 256, 0, stream>>>(f0, f1, f2, f3, f4, Wt, conv_b, cls_w,
                                     cls_b, bbox_w, bbox_b, scores,
                                     (float4*)boxes, cfg);

  topk_kernel<false><<<dim3(5, 2), 1024, 0, stream>>>(
      scores, (const float4*)boxes, topS, (float4*)allb, nullptr);
  nms_matrix<<<dim3(5, 2, 4), 256, 0, stream>>>((const float4*)allb, supp);
  nms_scan<<<dim3(5, 2), 64, 0, stream>>>(topS, supp, fscore);
  topk_kernel<true><<<2, 1024, 0, stream>>>(
      fscore, (const float4*)allb, nullptr, nullptr, out);
}